// Round 1
// baseline (10792.654 us; speedup 1.0000x reference)
//
#include <hip/hip_runtime.h>
#include <math.h>

static constexpr int C_IN    = 32;
static constexpr int T_STEPS = 12;
static constexpr int D_HID   = 128;
static constexpr int KTOT    = 3*C_IN + 3*D_HID;  // 480
static constexpr int GDIM    = 4*D_HID;           // 512

static inline int cdiv(long a, int b) { return (int)((a + b - 1) / b); }

// ---------------- CSR build ----------------

__global__ void k_zero_i(int* __restrict__ p, int n) {
  int i = blockIdx.x*blockDim.x + threadIdx.x;
  if (i < n) p[i] = 0;
}

__global__ void k_count(const int* __restrict__ src, const int* __restrict__ dst,
                        int* __restrict__ cnt, int* __restrict__ deg, int E) {
  int e = blockIdx.x*blockDim.x + threadIdx.x;
  if (e < E) {
    atomicAdd(&cnt[dst[e]], 1);   // group-by-dst counts (CSR rows)
    atomicAdd(&deg[src[e]], 1);   // out-degree of src (normalization)
  }
}

__global__ void k_dis(const int* __restrict__ deg, float* __restrict__ dis, int n) {
  int i = blockIdx.x*blockDim.x + threadIdx.x;
  if (i < n) {
    int d = deg[i];
    dis[i] = d > 0 ? rsqrtf((float)d) : 0.0f;
  }
}

__global__ __launch_bounds__(1024) void k_scan(const int* __restrict__ cnt,
                                               int* __restrict__ rowptr, int n) {
  __shared__ int wsum[16];
  __shared__ int carry_s;
  int tid = threadIdx.x; int lane = tid & 63; int wv_ = tid >> 6;
  if (tid == 0) { carry_s = 0; rowptr[0] = 0; }
  __syncthreads();
  for (int base = 0; base < n; base += 1024) {
    int i = base + tid;
    int s = (i < n) ? cnt[i] : 0;
    #pragma unroll
    for (int off = 1; off < 64; off <<= 1) {
      int t = __shfl_up(s, off);
      if (lane >= off) s += t;
    }
    if (lane == 63) wsum[wv_] = s;
    __syncthreads();
    if (tid < 16) {
      int ws = wsum[tid];
      #pragma unroll
      for (int off = 1; off < 16; off <<= 1) {
        int t = __shfl_up(ws, off);
        if (tid >= off) ws += t;
      }
      wsum[tid] = ws;
    }
    __syncthreads();
    int offw = carry_s + (wv_ > 0 ? wsum[wv_-1] : 0);
    if (i < n) rowptr[i+1] = offw + s;
    __syncthreads();
    if (tid == 0) carry_s = carry_s + wsum[15];
    __syncthreads();
  }
}

__global__ void k_fill(const int* __restrict__ src, const int* __restrict__ dst,
                       const int* __restrict__ rowptr, int* __restrict__ fil,
                       const float* __restrict__ dis,
                       int* __restrict__ colI, float* __restrict__ wvv, int E) {
  int e = blockIdx.x*blockDim.x + threadIdx.x;
  if (e < E) {
    int d = dst[e], s = src[e];
    int p = rowptr[d] + atomicAdd(&fil[d], 1);
    colI[p] = s;
    wvv[p] = -dis[s] * dis[d];
  }
}

// ---------------- weight packing: Bpack[KTOT][GDIM] ----------------
// rows 0..95   : k*32+c  -> Wx[g][k][c][d]   at col g*128+d
// rows 96..479 : k*128+j -> Wh[g][k][j][d]

__global__ void k_packB(const float* __restrict__ Wx, const float* __restrict__ Wh,
                        float* __restrict__ Bp) {
  int idx = blockIdx.x*blockDim.x + threadIdx.x;
  if (idx >= KTOT*GDIM) return;
  int kk = idx / GDIM, col = idx % GDIM;
  int g = col >> 7, d = col & 127;
  float v;
  if (kk < 96) {
    int k = kk >> 5, c = kk & 31;
    v = Wx[(size_t)(((g*3 + k)*32 + c) << 7) + d];
  } else {
    int kk2 = kk - 96;
    int k = kk2 >> 7, j = kk2 & 127;
    v = Wh[(size_t)(((g*3 + k)*128 + j) << 7) + d];
  }
  Bp[idx] = v;
}

// ---------------- per-timestep staging into ACAT[N][480] ----------------

__global__ void k_xt(const float* __restrict__ x, float* __restrict__ ACAT, int N, int t) {
  int i = blockIdx.x*blockDim.x + threadIdx.x;
  if (i >= N*C_IN) return;
  int n = i >> 5, c = i & 31;
  ACAT[(size_t)n*KTOT + c] = x[(size_t)i*T_STEPS + t];
}

__global__ void k_copyh(const float* __restrict__ h, float* __restrict__ ACAT, int N) {
  int i = blockIdx.x*blockDim.x + threadIdx.x;
  if (i >= N*D_HID) return;
  int n = i >> 7, d = i & 127;
  ACAT[(size_t)n*KTOT + 96 + d] = h ? h[i] : 0.0f;
}

// out[n*ostride+f] = alpha * sum_e w[e]*v[col[e]*vstride+f]  (- sub[n*substride+f] if sub)
template<int F>
__global__ void k_spmm(const int* __restrict__ rowptr, const int* __restrict__ colI,
                       const float* __restrict__ wvv,
                       const float* __restrict__ v, int vstride,
                       float* __restrict__ out, int ostride,
                       const float* __restrict__ sub, int substride,
                       float alpha, int n) {
  constexpr int LPN = (F < 64) ? F : 64;   // lanes per node
  constexpr int FPL = F / LPN;             // floats per lane
  int gt = blockIdx.x*blockDim.x + threadIdx.x;
  int node = gt / LPN;
  int lane = gt % LPN;
  if (node >= n) return;
  float acc[FPL];
  #pragma unroll
  for (int q = 0; q < FPL; ++q) acc[q] = 0.0f;
  if (v) {
    int r0 = rowptr[node], r1 = rowptr[node+1];
    for (int e = r0; e < r1; ++e) {
      int s = colI[e];
      float w = wvv[e];
      const float* vp = v + (size_t)s*vstride + lane;
      #pragma unroll
      for (int q = 0; q < FPL; ++q) acc[q] += w * vp[q*LPN];
    }
  }
  float* op = out + (size_t)node*ostride + lane;
  #pragma unroll
  for (int q = 0; q < FPL; ++q) {
    float r = alpha * acc[q];
    if (sub) r -= sub[(size_t)node*substride + lane + q*LPN];
    op[q*LPN] = r;
  }
}

// ---------------- GEMM: GATES[N][512] = ACAT[N][480] @ Bp[480][512] ----------------

__global__ __launch_bounds__(256) void k_gemm(const float* __restrict__ A,
                                              const float* __restrict__ B,
                                              float* __restrict__ Cg, int M) {
  __shared__ float As[16][65];    // [k][m], padded stride 65
  __shared__ float Bs[16][128];   // [k][n]
  int bm = blockIdx.y * 64;
  int bn = blockIdx.x * 128;
  int tid = threadIdx.x;
  int tcol = (tid & 15) * 8;
  int trow = (tid >> 4) * 4;
  float acc[4][8] = {};
  int am = tid >> 2;          // 0..63
  int ak = (tid & 3) * 4;     // 0,4,8,12
  int bk = tid >> 4;          // 0..15
  int bnn = (tid & 15) * 8;   // 0..120
  for (int k0 = 0; k0 < KTOT; k0 += 16) {
    int arow = bm + am;
    float4 av = make_float4(0.f, 0.f, 0.f, 0.f);
    if (arow < M) av = *(const float4*)(A + (size_t)arow*KTOT + k0 + ak);
    As[ak  ][am] = av.x; As[ak+1][am] = av.y;
    As[ak+2][am] = av.z; As[ak+3][am] = av.w;
    const float* bp = B + (size_t)(k0 + bk)*GDIM + bn + bnn;
    *(float4*)&Bs[bk][bnn]   = *(const float4*)bp;
    *(float4*)&Bs[bk][bnn+4] = *(const float4*)(bp + 4);
    __syncthreads();
    #pragma unroll
    for (int k = 0; k < 16; ++k) {
      float a0[4], b0[8];
      #pragma unroll
      for (int i = 0; i < 4; ++i) a0[i] = As[k][trow+i];
      #pragma unroll
      for (int j = 0; j < 8; ++j) b0[j] = Bs[k][tcol+j];
      #pragma unroll
      for (int i = 0; i < 4; ++i)
        #pragma unroll
        for (int j = 0; j < 8; ++j) acc[i][j] += a0[i]*b0[j];
    }
    __syncthreads();
  }
  #pragma unroll
  for (int i = 0; i < 4; ++i) {
    int row = bm + trow + i;
    if (row < M) {
      float* cp = Cg + (size_t)row*GDIM + bn + tcol;
      *(float4*)cp     = make_float4(acc[i][0], acc[i][1], acc[i][2], acc[i][3]);
      *(float4*)(cp+4) = make_float4(acc[i][4], acc[i][5], acc[i][6], acc[i][7]);
    }
  }
}

// ---------------- LSTM cell elementwise ----------------

__global__ void k_lstm(const float* __restrict__ G, float* __restrict__ Cst,
                       const float* __restrict__ bx, const float* __restrict__ bh,
                       const float* __restrict__ wc, const float* __restrict__ bg,
                       float* __restrict__ Ht, int N, int first) {
  int i = blockIdx.x*blockDim.x + threadIdx.x;
  if (i >= N*D_HID) return;
  int n = i >> 7, d = i & 127;
  const float* g = G + (size_t)n*GDIM;
  float c = first ? 0.0f : Cst[i];
  float gi = g[d]     + bx[d]     + bh[d]     + wc[d]*c     + bg[d];
  float gf = g[128+d] + bx[128+d] + bh[128+d] + wc[128+d]*c + bg[128+d];
  float gc = g[256+d] + bx[256+d] + bh[256+d]               + bg[256+d];
  float go = g[384+d] + bx[384+d] + bh[384+d]               + bg[384+d];
  float ig = 1.0f/(1.0f+expf(-gi));
  float fg = 1.0f/(1.0f+expf(-gf));
  float cn = fg*c + ig*tanhf(gc);
  float og = 1.0f/(1.0f+expf(-(go + wc[256+d]*cn)));
  float hn = og*tanhf(cn);
  Cst[i] = cn;
  Ht[i] = hn;
}

// ---------------- final tanh + LayerNorm (in place on d_out) ----------------

__global__ __launch_bounds__(256) void k_ln(float* __restrict__ H, const float* __restrict__ gam,
                                            const float* __restrict__ bet, long rows) {
  long row = (long)blockIdx.x*4 + (threadIdx.x >> 6);
  int lane = threadIdx.x & 63;
  if (row >= rows) return;
  float* p = H + row*(long)D_HID;
  float a = tanhf(p[lane]);
  float b = tanhf(p[lane+64]);
  float s = a + b, q = a*a + b*b;
  #pragma unroll
  for (int off = 32; off > 0; off >>= 1) {
    s += __shfl_xor(s, off);
    q += __shfl_xor(q, off);
  }
  float mu  = s * (1.0f/128.0f);
  float var = q * (1.0f/128.0f) - mu*mu;
  float rs  = rsqrtf(var + 1e-5f);
  p[lane]    = (a - mu)*rs*gam[lane]    + bet[lane];
  p[lane+64] = (b - mu)*rs*gam[lane+64] + bet[lane+64];
}

// ---------------- launch ----------------

extern "C" void kernel_launch(void* const* d_in, const int* in_sizes, int n_in,
                              void* d_out, int out_size, void* d_ws, size_t ws_size,
                              hipStream_t stream) {
  const float* x   = (const float*)d_in[0];
  const int*   ei  = (const int*)  d_in[1];
  const float* Wx  = (const float*)d_in[2];
  const float* bx  = (const float*)d_in[3];
  const float* Wh  = (const float*)d_in[4];
  const float* bh  = (const float*)d_in[5];
  const float* wc  = (const float*)d_in[6];
  const float* bg  = (const float*)d_in[7];
  const float* lng = (const float*)d_in[8];
  const float* lnb = (const float*)d_in[9];
  const int N = in_sizes[0] / (C_IN*T_STEPS);
  const int E = in_sizes[1] / 2;
  const int* src = ei;
  const int* dst = ei + E;
  float* Hout = (float*)d_out;

  char* w = (char*)d_ws;
  auto alloc = [&](size_t bytes) -> char* {
    char* p = w; w += (bytes + 255) & ~size_t(255); return p;
  };
  float* ACAT  = (float*)alloc((size_t)N*KTOT*4);
  float* GATES = (float*)alloc((size_t)N*GDIM*4);
  float* Cst   = (float*)alloc((size_t)N*D_HID*4);
  int*   aux   = (int*)  alloc((size_t)3*N*4);   // cnt | fill | deg
  float* dis   = (float*)alloc((size_t)N*4);
  int*   rowptr= (int*)  alloc((size_t)(N+1)*4);
  int*   colI  = (int*)  alloc((size_t)E*4);
  float* wvv   = (float*)alloc((size_t)E*4);
  float* Bp    = (float*)alloc((size_t)KTOT*GDIM*4);
  if ((size_t)(w - (char*)d_ws) > ws_size) return;  // insufficient workspace

  int* cnt = aux; int* fil = aux + N; int* deg = aux + 2*N;

  // CSR + normalization (rebuilt every call; no state carried across calls)
  k_zero_i<<<cdiv(3L*N,256),256,0,stream>>>(aux, 3*N);
  k_count<<<cdiv(E,256),256,0,stream>>>(src, dst, cnt, deg, E);
  k_dis<<<cdiv(N,256),256,0,stream>>>(deg, dis, N);
  k_scan<<<1,1024,0,stream>>>(cnt, rowptr, N);
  k_fill<<<cdiv(E,256),256,0,stream>>>(src, dst, rowptr, fil, dis, colI, wvv, E);
  k_packB<<<cdiv((long)KTOT*GDIM,256),256,0,stream>>>(Wx, Wh, Bp);

  dim3 ggrid(GDIM/128, cdiv(N,64));
  for (int t = 0; t < T_STEPS; ++t) {
    const float* hprev = (t == 0) ? nullptr : Hout + (size_t)(t-1)*N*D_HID;
    // x-side Chebyshev basis -> ACAT cols [0,96)
    k_xt<<<cdiv((long)N*C_IN,256),256,0,stream>>>(x, ACAT, N, t);
    k_spmm<32><<<cdiv((long)N*32,256),256,0,stream>>>(rowptr, colI, wvv,
        ACAT + 0, KTOT, ACAT + 32, KTOT, nullptr, 0, 1.0f, N);
    k_spmm<32><<<cdiv((long)N*32,256),256,0,stream>>>(rowptr, colI, wvv,
        ACAT + 32, KTOT, ACAT + 64, KTOT, ACAT + 0, KTOT, 2.0f, N);
    // h-side Chebyshev basis -> ACAT cols [96,480)
    k_copyh<<<cdiv((long)N*D_HID,256),256,0,stream>>>(hprev, ACAT, N);
    k_spmm<128><<<cdiv((long)N*64,256),256,0,stream>>>(rowptr, colI, wvv,
        hprev, D_HID, ACAT + 224, KTOT, nullptr, 0, 1.0f, N);
    k_spmm<128><<<cdiv((long)N*64,256),256,0,stream>>>(rowptr, colI, wvv,
        ACAT + 224, KTOT, ACAT + 352, KTOT, hprev, D_HID, 2.0f, N);
    // all 4 gates in one GEMM
    k_gemm<<<ggrid,256,0,stream>>>(ACAT, Bp, GATES, N);
    // LSTM cell; h_new written straight into d_out[t]
    k_lstm<<<cdiv((long)N*D_HID,256),256,0,stream>>>(GATES, Cst, bx, bh, wc, bg,
        Hout + (size_t)t*N*D_HID, N, t == 0 ? 1 : 0);
  }
  k_ln<<<cdiv((long)T_STEPS*N,4),256,0,stream>>>(Hout, lng, lnb, (long)T_STEPS*N);
}

// Round 4
// 7860.284 us; speedup vs baseline: 1.3731x; 1.3731x over previous
//
#include <hip/hip_runtime.h>
#include <math.h>

static constexpr int C_IN    = 32;
static constexpr int T_STEPS = 12;
static constexpr int D_HID   = 128;
static constexpr int KTOT    = 3*C_IN + 3*D_HID;  // 480
static constexpr int GDIM    = 4*D_HID;           // 512

static inline int cdiv(long a, int b) { return (int)((a + b - 1) / b); }

typedef __attribute__((ext_vector_type(8))) short bf16x8;
typedef __attribute__((ext_vector_type(4))) float f32x4;

__device__ __forceinline__ float bf2f(unsigned int u16) {
  union { unsigned int u; float f; } v; v.u = u16 << 16; return v.f;
}
__device__ __forceinline__ unsigned short f2bf(float f) {
  union { float f; unsigned int u; } v; v.f = f;
  unsigned int u = v.u + 0x7fffu + ((v.u >> 16) & 1u);  // RNE
  return (unsigned short)(u >> 16);
}
__device__ __forceinline__ void split2(float a, unsigned short& h, unsigned short& l) {
  h = f2bf(a);
  l = f2bf(a - bf2f(h));
}

// ---------------- CSR build ----------------

__global__ void k_zero_i(int* __restrict__ p, int n) {
  int i = blockIdx.x*blockDim.x + threadIdx.x;
  if (i < n) p[i] = 0;
}

__global__ void k_count(const int* __restrict__ src, const int* __restrict__ dst,
                        int* __restrict__ cnt, int* __restrict__ deg, int E) {
  int e = blockIdx.x*blockDim.x + threadIdx.x;
  if (e < E) {
    atomicAdd(&cnt[dst[e]], 1);
    atomicAdd(&deg[src[e]], 1);
  }
}

__global__ void k_dis(const int* __restrict__ deg, float* __restrict__ dis, int n) {
  int i = blockIdx.x*blockDim.x + threadIdx.x;
  if (i < n) {
    int d = deg[i];
    dis[i] = d > 0 ? rsqrtf((float)d) : 0.0f;
  }
}

__global__ __launch_bounds__(1024) void k_scan(const int* __restrict__ cnt,
                                               int* __restrict__ rowptr, int n) {
  __shared__ int wsum[16];
  __shared__ int carry_s;
  int tid = threadIdx.x; int lane = tid & 63; int wv_ = tid >> 6;
  if (tid == 0) { carry_s = 0; rowptr[0] = 0; }
  __syncthreads();
  for (int base = 0; base < n; base += 1024) {
    int i = base + tid;
    int s = (i < n) ? cnt[i] : 0;
    #pragma unroll
    for (int off = 1; off < 64; off <<= 1) {
      int t = __shfl_up(s, off);
      if (lane >= off) s += t;
    }
    if (lane == 63) wsum[wv_] = s;
    __syncthreads();
    if (tid < 16) {
      int ws = wsum[tid];
      #pragma unroll
      for (int off = 1; off < 16; off <<= 1) {
        int t = __shfl_up(ws, off);
        if (tid >= off) ws += t;
      }
      wsum[tid] = ws;
    }
    __syncthreads();
    int offw = carry_s + (wv_ > 0 ? wsum[wv_-1] : 0);
    if (i < n) rowptr[i+1] = offw + s;
    __syncthreads();
    if (tid == 0) carry_s = carry_s + wsum[15];
    __syncthreads();
  }
}

__global__ void k_fill(const int* __restrict__ src, const int* __restrict__ dst,
                       const int* __restrict__ rowptr, int* __restrict__ fil,
                       const float* __restrict__ dis,
                       int* __restrict__ colI, float* __restrict__ wvv, int E) {
  int e = blockIdx.x*blockDim.x + threadIdx.x;
  if (e < E) {
    int d = dst[e], s = src[e];
    int p = rowptr[d] + atomicAdd(&fil[d], 1);
    colI[p] = s;
    wvv[p] = -dis[s] * dis[d];
  }
}

// ---------------- weight packing: k8-interleaved hi/lo ----------------
// element (kk, col) stored at ((kt*4+kg)*512 + col)*8 + i, kk = kt*32+kg*8+i

__global__ void k_packB(const float* __restrict__ Wx, const float* __restrict__ Wh,
                        unsigned short* __restrict__ BH, unsigned short* __restrict__ BL) {
  int idx = blockIdx.x*blockDim.x + threadIdx.x;
  if (idx >= KTOT*GDIM) return;
  int kk = idx / GDIM, col = idx % GDIM;
  int g = col >> 7, d = col & 127;
  float v;
  if (kk < 96) {
    int k = kk >> 5, c = kk & 31;
    v = Wx[(size_t)(((g*3 + k)*32 + c) << 7) + d];
  } else {
    int kk2 = kk - 96;
    int k = kk2 >> 7, j = kk2 & 127;
    v = Wh[(size_t)(((g*3 + k)*128 + j) << 7) + d];
  }
  unsigned short h, l; split2(v, h, l);
  int kt = kk >> 5, kg = (kk >> 3) & 3, i = kk & 7;
  size_t o = ((size_t)((kt*4 + kg)*GDIM + col))*8 + i;
  BH[o] = h; BL[o] = l;
}

// ---------------- staging ----------------

__global__ void k_xt(const float* __restrict__ x, unsigned short* __restrict__ AH,
                     unsigned short* __restrict__ AL, int N, int t) {
  int i = blockIdx.x*blockDim.x + threadIdx.x;
  if (i >= N*C_IN) return;
  int n = i >> 5, c = i & 31;
  float v = x[(size_t)i*T_STEPS + t];
  unsigned short h, l; split2(v, h, l);
  AH[(size_t)n*KTOT + c] = h;
  AL[(size_t)n*KTOT + c] = l;
}

// zero h-basis cols [96,480) (uints 48..239 of each 240-uint row)
__global__ void k_zeroh(unsigned int* __restrict__ AH, unsigned int* __restrict__ AL, int N) {
  int i = blockIdx.x*blockDim.x + threadIdx.x;
  if (i >= N*192) return;
  int n = i / 192, j = i - n*192;
  size_t o = (size_t)n*240 + 48 + j;
  AH[o] = 0u; AL[o] = 0u;
}

// out[colO..colO+F) = alpha * (L_hat @ v[colV..colV+F)) - (colS>=0 ? v_self[colS..] : 0)
template<int F>
__global__ void k_spmm(const int* __restrict__ rowptr, const int* __restrict__ colI,
                       const float* __restrict__ wvv,
                       unsigned short* __restrict__ AH, unsigned short* __restrict__ AL,
                       int colV, int colO, int colS, float alpha, int n) {
  constexpr int LPN = F/2;   // lanes per node, each lane covers 2 elems via uint
  int gt = blockIdx.x*blockDim.x + threadIdx.x;
  int node = gt / LPN;
  int lane = gt & (LPN-1);
  if (node >= n) return;
  const unsigned int* AHu = (const unsigned int*)AH;
  const unsigned int* ALu = (const unsigned int*)AL;
  float a0 = 0.f, a1 = 0.f;
  int r0 = rowptr[node], r1 = rowptr[node+1];
  for (int e = r0; e < r1; ++e) {
    int s = colI[e];
    float wv = wvv[e];
    size_t bi = (((size_t)s*KTOT + colV) >> 1) + lane;
    unsigned int uh = AHu[bi], ul = ALu[bi];
    a0 += wv * (bf2f(uh & 0xffffu) + bf2f(ul & 0xffffu));
    a1 += wv * (bf2f(uh >> 16)     + bf2f(ul >> 16));
  }
  float o0 = alpha*a0, o1 = alpha*a1;
  if (colS >= 0) {
    size_t si = (((size_t)node*KTOT + colS) >> 1) + lane;
    unsigned int sh = AHu[si], sl = ALu[si];
    o0 -= bf2f(sh & 0xffffu) + bf2f(sl & 0xffffu);
    o1 -= bf2f(sh >> 16)     + bf2f(sl >> 16);
  }
  unsigned short h0, l0, h1, l1;
  split2(o0, h0, l0); split2(o1, h1, l1);
  size_t oi = (((size_t)node*KTOT + colO) >> 1) + lane;
  ((unsigned int*)AH)[oi] = (unsigned int)h0 | ((unsigned int)h1 << 16);
  ((unsigned int*)AL)[oi] = (unsigned int)l0 | ((unsigned int)l1 << 16);
}

// ---------------- MFMA GEMM: G[N][512] = (AH+AL)[N][480] @ (BH+BL)[480][512] ----------------
// bf16x3: acc += Ah*Bh + Ah*Bl + Al*Bh   (f32 accumulate)

__global__ __launch_bounds__(256) void k_gemm(const unsigned short* __restrict__ AH,
                                              const unsigned short* __restrict__ AL,
                                              const unsigned short* __restrict__ BH,
                                              const unsigned short* __restrict__ BL,
                                              float* __restrict__ G, int M) {
  __shared__ unsigned short As[2][128][40];   // [hi/lo][row][k], pad 40 (bank-spread)
  __shared__ unsigned short Bs[2][4][1040];   // [hi/lo][kg][col*8+i], pad 1040 (bank-spread)
  const int tid = threadIdx.x;
  const int bm = blockIdx.y * 128;
  const int bn = blockIdx.x * 128;
  const int lane = tid & 63;
  const int wid = tid >> 6;
  const int wr = wid >> 1;
  const int wc = wid & 1;
  const int l15 = lane & 15;
  const int l4  = lane >> 4;
  f32x4 acc[4][4] = {};
  for (int kt = 0; kt < KTOT/32; ++kt) {
    const int k0 = kt*32;
    __syncthreads();
    #pragma unroll
    for (int r2 = 0; r2 < 2; ++r2) {
      int c = tid + 256*r2;
      int row = c >> 2, ko = (c & 3) * 8;
      size_t goff = (size_t)(bm + row)*KTOT + k0 + ko;
      uint4 vh = make_uint4(0,0,0,0), vl = make_uint4(0,0,0,0);
      if (bm + row < M) {
        vh = *(const uint4*)(AH + goff);
        vl = *(const uint4*)(AL + goff);
      }
      *(uint4*)&As[0][row][ko] = vh;
      *(uint4*)&As[1][row][ko] = vl;
      int kg = c >> 7, col = c & 127;
      size_t bo = ((size_t)((kt*4 + kg)*GDIM + bn + col))*8;
      *(uint4*)&Bs[0][kg][col*8] = *(const uint4*)(BH + bo);
      *(uint4*)&Bs[1][kg][col*8] = *(const uint4*)(BL + bo);
    }
    __syncthreads();
    bf16x8 ah[4], al[4];
    #pragma unroll
    for (int mi = 0; mi < 4; ++mi) {
      int r = wr*64 + mi*16 + l15;
      ah[mi] = *(const bf16x8*)&As[0][r][l4*8];
      al[mi] = *(const bf16x8*)&As[1][r][l4*8];
    }
    #pragma unroll
    for (int ni = 0; ni < 4; ++ni) {
      int cidx = (wc*64 + ni*16 + l15)*8;
      bf16x8 bh = *(const bf16x8*)&Bs[0][l4][cidx];
      bf16x8 bl = *(const bf16x8*)&Bs[1][l4][cidx];
      #pragma unroll
      for (int mi = 0; mi < 4; ++mi) {
        acc[mi][ni] = __builtin_amdgcn_mfma_f32_16x16x32_bf16(ah[mi], bh, acc[mi][ni], 0,0,0);
        acc[mi][ni] = __builtin_amdgcn_mfma_f32_16x16x32_bf16(ah[mi], bl, acc[mi][ni], 0,0,0);
        acc[mi][ni] = __builtin_amdgcn_mfma_f32_16x16x32_bf16(al[mi], bh, acc[mi][ni], 0,0,0);
      }
    }
  }
  #pragma unroll
  for (int mi = 0; mi < 4; ++mi) {
    #pragma unroll
    for (int q = 0; q < 4; ++q) {
      int row = bm + wr*64 + mi*16 + l4*4 + q;
      if (row < M) {
        #pragma unroll
        for (int ni = 0; ni < 4; ++ni) {
          G[(size_t)row*GDIM + bn + wc*64 + ni*16 + l15] = acc[mi][ni][q];
        }
      }
    }
  }
}

// ---------------- LSTM cell elementwise (h also written as hi/lo into ACAT) ----------------

__global__ void k_lstm(const float* __restrict__ G, float* __restrict__ Cst,
                       const float* __restrict__ bx, const float* __restrict__ bh,
                       const float* __restrict__ wc, const float* __restrict__ bg,
                       float* __restrict__ Ht,
                       unsigned short* __restrict__ AH, unsigned short* __restrict__ AL,
                       int N, int first) {
  int i = blockIdx.x*blockDim.x + threadIdx.x;
  if (i >= N*D_HID) return;
  int n = i >> 7, d = i & 127;
  const float* g = G + (size_t)n*GDIM;
  float c = first ? 0.0f : Cst[i];
  float gi = g[d]     + bx[d]     + bh[d]     + wc[d]*c     + bg[d];
  float gf = g[128+d] + bx[128+d] + bh[128+d] + wc[128+d]*c + bg[128+d];
  float gc = g[256+d] + bx[256+d] + bh[256+d]               + bg[256+d];
  float go = g[384+d] + bx[384+d] + bh[384+d]               + bg[384+d];
  float ig = 1.0f/(1.0f+expf(-gi));
  float fg = 1.0f/(1.0f+expf(-gf));
  float cn = fg*c + ig*tanhf(gc);
  float og = 1.0f/(1.0f+expf(-(go + wc[256+d]*cn)));
  float hn = og*tanhf(cn);
  Cst[i] = cn;
  Ht[i] = hn;
  unsigned short h, l; split2(hn, h, l);
  size_t o = (size_t)n*KTOT + 96 + d;
  AH[o] = h; AL[o] = l;
}

// ---------------- final tanh + LayerNorm (in place on d_out) ----------------

__global__ __launch_bounds__(256) void k_ln(float* __restrict__ H, const float* __restrict__ gam,
                                            const float* __restrict__ bet, long rows) {
  long row = (long)blockIdx.x*4 + (threadIdx.x >> 6);
  int lane = threadIdx.x & 63;
  if (row >= rows) return;
  float* p = H + row*(long)D_HID;
  float a = tanhf(p[lane]);
  float b = tanhf(p[lane+64]);
  float s = a + b, q = a*a + b*b;
  #pragma unroll
  for (int off = 32; off > 0; off >>= 1) {
    s += __shfl_xor(s, off);
    q += __shfl_xor(q, off);
  }
  float mu  = s * (1.0f/128.0f);
  float var = q * (1.0f/128.0f) - mu*mu;
  float rs  = rsqrtf(var + 1e-5f);
  p[lane]    = (a - mu)*rs*gam[lane]    + bet[lane];
  p[lane+64] = (b - mu)*rs*gam[lane+64] + bet[lane+64];
}

// ---------------- launch ----------------

extern "C" void kernel_launch(void* const* d_in, const int* in_sizes, int n_in,
                              void* d_out, int out_size, void* d_ws, size_t ws_size,
                              hipStream_t stream) {
  const float* x   = (const float*)d_in[0];
  const int*   ei  = (const int*)  d_in[1];
  const float* Wx  = (const float*)d_in[2];
  const float* bx  = (const float*)d_in[3];
  const float* Wh  = (const float*)d_in[4];
  const float* bh  = (const float*)d_in[5];
  const float* wc  = (const float*)d_in[6];
  const float* bg  = (const float*)d_in[7];
  const float* lng = (const float*)d_in[8];
  const float* lnb = (const float*)d_in[9];
  const int N = in_sizes[0] / (C_IN*T_STEPS);
  const int E = in_sizes[1] / 2;
  const int* src = ei;
  const int* dst = ei + E;
  float* Hout = (float*)d_out;

  char* w = (char*)d_ws;
  auto alloc = [&](size_t bytes) -> char* {
    char* p = w; w += (bytes + 255) & ~size_t(255); return p;
  };
  unsigned short* AH = (unsigned short*)alloc((size_t)N*KTOT*2);
  unsigned short* AL = (unsigned short*)alloc((size_t)N*KTOT*2);
  float* GATES = (float*)alloc((size_t)N*GDIM*4);
  float* Cst   = (float*)alloc((size_t)N*D_HID*4);
  int*   aux   = (int*)  alloc((size_t)3*N*4);
  float* dis   = (float*)alloc((size_t)N*4);
  int*   rowptr= (int*)  alloc((size_t)(N+1)*4);
  int*   colI  = (int*)  alloc((size_t)E*4);
  float* wvv   = (float*)alloc((size_t)E*4);
  unsigned short* BH = (unsigned short*)alloc((size_t)KTOT*GDIM*2);
  unsigned short* BL = (unsigned short*)alloc((size_t)KTOT*GDIM*2);
  if ((size_t)(w - (char*)d_ws) > ws_size) return;

  int* cnt = aux; int* fil = aux + N; int* deg = aux + 2*N;

  k_zero_i<<<cdiv(3L*N,256),256,0,stream>>>(aux, 3*N);
  k_count<<<cdiv(E,256),256,0,stream>>>(src, dst, cnt, deg, E);
  k_dis<<<cdiv(N,256),256,0,stream>>>(deg, dis, N);
  k_scan<<<1,1024,0,stream>>>(cnt, rowptr, N);
  k_fill<<<cdiv(E,256),256,0,stream>>>(src, dst, rowptr, fil, dis, colI, wvv, E);
  k_packB<<<cdiv((long)KTOT*GDIM,256),256,0,stream>>>(Wx, Wh, BH, BL);
  k_zeroh<<<cdiv((long)N*192,256),256,0,stream>>>((unsigned int*)AH, (unsigned int*)AL, N);

  dim3 ggrid(GDIM/128, cdiv(N,128));
  for (int t = 0; t < T_STEPS; ++t) {
    // x-side Chebyshev basis -> cols [0,96)
    k_xt<<<cdiv((long)N*C_IN,256),256,0,stream>>>(x, AH, AL, N, t);
    k_spmm<32><<<cdiv((long)N*16,256),256,0,stream>>>(rowptr, colI, wvv,
        AH, AL, 0, 32, -1, 1.0f, N);
    k_spmm<32><<<cdiv((long)N*16,256),256,0,stream>>>(rowptr, colI, wvv,
        AH, AL, 32, 64, 0, 2.0f, N);
    // h-side Chebyshev basis -> cols [224,480)  (h itself at [96,224) from k_lstm)
    if (t > 0) {
      k_spmm<128><<<cdiv((long)N*64,256),256,0,stream>>>(rowptr, colI, wvv,
          AH, AL, 96, 224, -1, 1.0f, N);
      k_spmm<128><<<cdiv((long)N*64,256),256,0,stream>>>(rowptr, colI, wvv,
          AH, AL, 224, 352, 96, 2.0f, N);
    }
    // all 4 gates in one bf16x3 MFMA GEMM
    k_gemm<<<ggrid,256,0,stream>>>(AH, AL, BH, BL, GATES, N);
    // LSTM cell; h_new -> d_out[t] (f32) and ACAT cols [96,224) (hi/lo)
    k_lstm<<<cdiv((long)N*D_HID,256),256,0,stream>>>(GATES, Cst, bx, bh, wc, bg,
        Hout + (size_t)t*N*D_HID, AH, AL, N, t == 0 ? 1 : 0);
  }
  k_ln<<<cdiv((long)T_STEPS*N,4),256,0,stream>>>(Hout, lng, lnb, (long)T_STEPS*N);
}